// Round 13
// baseline (136.396 us; speedup 1.0000x reference)
//
#include <hip/hip_runtime.h>
#include <math.h>

#define EPS 1e-5f
#define N0 1000
#define NK1 500
#define NK2 100
#define NE 32000

__device__ __forceinline__ float bnr(float h, float sc, float sh) {
    float v = fmaf(h, sc, sh);
    return v > 0.f ? v : 0.f;
}

// ==== K1: lin0+lin1 fused (64 blocks x 16 nodes) + zero sc1/sc2 =============
__global__ __launch_bounds__(256) void k_lin01(
        const float* __restrict__ x, const float* __restrict__ w0,
        const float* __restrict__ b0, const float* __restrict__ g0,
        const float* __restrict__ be0, const float* __restrict__ w1,
        const float* __restrict__ b1, float* __restrict__ h1,
        float* __restrict__ psum1, float* __restrict__ sc1, float* __restrict__ sc2) {
    __shared__ float xs[16][68], wsm[64][65];
    __shared__ float sc0[64], sh0[64];
    __shared__ float redA[256], redB[256];
    const int b = blockIdx.x, t = threadIdx.x;
    const int c = t & 63, slot = t >> 6;
    const int nb = b * 16;

    int gid = b * 256 + t;
    if (gid < 1000) sc1[gid] = 0.f;
    else if (gid < 1500) sc2[gid - 1000] = 0.f;

    // redundant BN0 stats (cached x reads, pure VALU)
    {
        float wa = w0[c * 3], wb_ = w0[c * 3 + 1], wc_ = w0[c * 3 + 2], bb = b0[c];
        float s = 0.f, q = 0.f;
        for (int n = slot; n < N0; n += 4) {
            float h = fmaf(wa, x[n * 3], fmaf(wb_, x[n * 3 + 1], fmaf(wc_, x[n * 3 + 2], bb)));
            s += h; q += h * h;
        }
        redA[t] = s; redB[t] = q;
        __syncthreads();
        if (t < 64) {
            float S = redA[t] + redA[t + 64] + redA[t + 128] + redA[t + 192];
            float Q = redB[t] + redB[t + 64] + redB[t + 128] + redB[t + 192];
            float mu = S * (1.f / N0);
            float var = Q * (1.f / N0) - mu * mu;
            float sv = g0[t] * rsqrtf(var + EPS);
            sc0[t] = sv; sh0[t] = be0[t] - mu * sv;
        }
        __syncthreads();
    }
    // y0 tile (recompute h0 + BN0 relu) + w1 staging
    for (int i = 0; i < 4; ++i) {
        int e = t + i * 256;
        int r = e >> 6, cc = e & 63;
        int n = nb + r;
        float v = 0.f;
        if (n < N0) {
            float h = fmaf(w0[cc * 3], x[n * 3],
                      fmaf(w0[cc * 3 + 1], x[n * 3 + 1],
                      fmaf(w0[cc * 3 + 2], x[n * 3 + 2], b0[cc])));
            v = bnr(h, sc0[cc], sh0[cc]);
        }
        xs[r][cc] = v;
    }
    for (int i = 0; i < 16; ++i) {
        int e = t + i * 256;
        wsm[e >> 6][e & 63] = w1[e];
    }
    __syncthreads();
    const int r0 = slot * 4;
    float bb1 = b1[c];
    float a0 = bb1, a1 = bb1, a2 = bb1, a3 = bb1;
    #pragma unroll
    for (int kq = 0; kq < 16; ++kq) {
        float w0v = wsm[c][4 * kq],     w1v = wsm[c][4 * kq + 1];
        float w2v = wsm[c][4 * kq + 2], w3v = wsm[c][4 * kq + 3];
        float4 x0 = *(const float4*)&xs[r0 + 0][4 * kq];
        float4 x1 = *(const float4*)&xs[r0 + 1][4 * kq];
        float4 x2 = *(const float4*)&xs[r0 + 2][4 * kq];
        float4 x3 = *(const float4*)&xs[r0 + 3][4 * kq];
        a0 = fmaf(x0.x, w0v, fmaf(x0.y, w1v, fmaf(x0.z, w2v, fmaf(x0.w, w3v, a0))));
        a1 = fmaf(x1.x, w0v, fmaf(x1.y, w1v, fmaf(x1.z, w2v, fmaf(x1.w, w3v, a1))));
        a2 = fmaf(x2.x, w0v, fmaf(x2.y, w1v, fmaf(x2.z, w2v, fmaf(x2.w, w3v, a2))));
        a3 = fmaf(x3.x, w0v, fmaf(x3.y, w1v, fmaf(x3.z, w2v, fmaf(x3.w, w3v, a3))));
    }
    float av[4] = {a0, a1, a2, a3};
    float sacc = 0.f, qacc = 0.f;
    #pragma unroll
    for (int i = 0; i < 4; ++i) {
        int n = nb + r0 + i;
        if (n < N0) {
            h1[n * 64 + c] = av[i];
            sacc += av[i]; qacc += av[i] * av[i];
        }
    }
    __syncthreads();
    redA[t] = sacc; redB[t] = qacc;
    __syncthreads();
    if (t < 64) {
        psum1[b * 128 + t]      = redA[t] + redA[t + 64] + redA[t + 128] + redA[t + 192];
        psum1[b * 128 + 64 + t] = redB[t] + redB[t + 64] + redB[t + 128] + redB[t + 192];
    }
}

// ==== K2 (16 blocks): BN1 + t1-all + root-all + scatter1 ====================
__global__ __launch_bounds__(256) void k_pool1scat(
        const float* __restrict__ h1, const float* __restrict__ psum1,
        const float* __restrict__ g1, const float* __restrict__ be1,
        const float* __restrict__ wrel, const float* __restrict__ wroot,
        const float* __restrict__ pb, const int* __restrict__ ei,
        const float* __restrict__ ea, float* __restrict__ sc1) {
    __shared__ float tt[1008], rt[1008], acc[1008];
    __shared__ float bsc[64], bsh[64];
    __shared__ float red[128];
    const int b = blockIdx.x, t = threadIdx.x;
    if (t < 128) {
        float s = 0.f;
        for (int i = 0; i < 64; ++i) s += psum1[i * 128 + t];
        red[t] = s;
    }
    for (int i = t; i < 1008; i += 256) acc[i] = 0.f;
    __syncthreads();
    if (t < 64) {
        float mu = red[t] * (1.f / N0);
        float var = red[64 + t] * (1.f / N0) - mu * mu;
        float sv = g1[t] * rsqrtf(var + EPS);
        bsc[t] = sv; bsh[t] = be1[t] - mu * sv;
    }
    __syncthreads();
    // t1-all + root-all: 4-lane groups, 16 channels each (cached h1 reads)
    {
        const int sub = t & 3, grp = t >> 2;
        float wrv[16], wov[16], scv[16], shv[16];
        #pragma unroll
        for (int i = 0; i < 16; ++i) {
            int ch = sub * 16 + i;
            wrv[i] = wrel[ch]; wov[i] = wroot[ch];
            scv[i] = bsc[ch];  shv[i] = bsh[ch];
        }
        float pbv = pb[0];
        for (int p = 0; p < 16; ++p) {
            int n = p * 64 + grp;
            if (n < N0) {
                const float* hp = h1 + n * 64 + sub * 16;
                float dr = 0.f, dt = 0.f;
                #pragma unroll
                for (int i = 0; i < 16; ++i) {
                    float v = bnr(hp[i], scv[i], shv[i]);
                    dr = fmaf(v, wrv[i], dr);
                    dt = fmaf(v, wov[i], dt);
                }
                dr += __shfl_xor(dr, 1, 64); dr += __shfl_xor(dr, 2, 64);
                dt += __shfl_xor(dt, 1, 64); dt += __shfl_xor(dt, 2, 64);
                if (sub == 0) { tt[n] = dr; rt[n] = dt + pbv; }
            }
        }
    }
    __syncthreads();
    // scatter own 2000-edge slice into LDS acc
    for (int e = b * 2000 + t; e < b * 2000 + 2000; e += 256) {
        float w = ea[e];
        if (w != 0.f) atomicAdd(&acc[ei[NE + e]], w * tt[ei[e]]);
    }
    __syncthreads();
    // commit: own 63-node root slice + all nonzero acc
    {
        int n = b * 63 + t;
        if (t < 63 && n < N0) atomicAdd(&sc1[n], rt[n]);
    }
    for (int i = t; i < N0; i += 256) {
        float v = acc[i];
        if (v != 0.f) atomicAdd(&sc1[i], v);
    }
}

// ==== K3: rank1 + select + lin2a owner-computes (64 blocks x 16 nodes) ======
__global__ __launch_bounds__(256) void k_rank1_lin2a(
        const float* __restrict__ h1, const float* __restrict__ psum1,
        const float* __restrict__ g1, const float* __restrict__ be1,
        const float* __restrict__ sc1, const float* __restrict__ w2a,
        const float* __restrict__ b2a, float* __restrict__ h2a,
        float* __restrict__ psum2a, int* __restrict__ rk_g) {
    __shared__ float ss[N0];
    __shared__ float xp[16][68];
    __shared__ float wsm[128][65];
    __shared__ float bsc[64], bsh[64];
    __shared__ float red[256], redq[256];
    __shared__ int rloc[16], svj[16];
    __shared__ float thv[16];
    __shared__ int nsS;
    const int b = blockIdx.x, t = threadIdx.x;
    const int lane = t & 63, wv = t >> 6;
    const int nb = b * 16;
    const int nn = (N0 - nb) < 0 ? 0 : ((N0 - nb) < 16 ? (N0 - nb) : 16);

    for (int i = t; i < N0; i += 256) ss[i] = sc1[i];
    if (t < 128) {
        float s = 0.f;
        for (int i = 0; i < 64; ++i) s += psum1[i * 128 + t];
        red[t] = s;
    }
    __syncthreads();
    if (t < 64) {
        float mu = red[t] * (1.f / N0);
        float var = red[64 + t] * (1.f / N0) - mu * mu;
        float sv = g1[t] * rsqrtf(var + EPS);
        bsc[t] = sv; bsh[t] = be1[t] - mu * sv;
    }
    __syncthreads();
    for (int it = 0; it < 4; ++it) {
        int j = it * 4 + wv;
        int n = nb + j;
        if (j < nn) {
            float s = ss[n];
            int r = 0;
            for (int m = lane; m < N0; m += 64) {
                float x = ss[m];
                r += (x > s) || (x == s && m < n);
            }
            #pragma unroll
            for (int msk = 32; msk >= 1; msk >>= 1) r += __shfl_xor(r, msk, 64);
            if (lane == 0) { rk_g[n] = r; rloc[j] = r; }
        } else if (lane == 0) rloc[j] = 1 << 20;
    }
    __syncthreads();
    if (t == 0) {
        int c_ = 0;
        for (int j = 0; j < 16; ++j)
            if (rloc[j] < NK1) { svj[c_] = j; ++c_; }
        nsS = c_;
    }
    __syncthreads();
    const int ns = nsS;
    if (t < ns) thv[t] = tanhf(ss[nb + svj[t]]);
    __syncthreads();
    for (int e = t; e < 16 * 64; e += 256) {
        int i = e >> 6, c = e & 63;
        xp[i][c] = (i < ns) ? bnr(h1[(nb + svj[i]) * 64 + c], bsc[c], bsh[c]) * thv[i] : 0.f;
    }
    for (int e = t; e < 128 * 64; e += 256)
        wsm[e >> 6][e & 63] = w2a[e];
    __syncthreads();
    const int c2 = t & 127, half = t >> 7;
    float hac[8];
    {
        float bb = b2a[c2];
        #pragma unroll
        for (int i = 0; i < 8; ++i) hac[i] = bb;
    }
    #pragma unroll
    for (int kq = 0; kq < 16; ++kq) {
        float w0v = wsm[c2][4 * kq],     w1v = wsm[c2][4 * kq + 1];
        float w2v = wsm[c2][4 * kq + 2], w3v = wsm[c2][4 * kq + 3];
        #pragma unroll
        for (int i = 0; i < 8; ++i) {
            float4 x4 = *(const float4*)&xp[half * 8 + i][4 * kq];
            hac[i] = fmaf(x4.x, w0v, fmaf(x4.y, w1v, fmaf(x4.z, w2v, fmaf(x4.w, w3v, hac[i]))));
        }
    }
    float s = 0.f, q = 0.f;
    #pragma unroll
    for (int i = 0; i < 8; ++i) {
        int sl = half * 8 + i;
        if (sl < ns) {
            int r = rloc[svj[sl]];
            h2a[r * 128 + c2] = hac[i];
            s += hac[i]; q += hac[i] * hac[i];
        }
    }
    __syncthreads();
    red[t] = s; redq[t] = q;
    __syncthreads();
    if (t < 128) {
        psum2a[b * 256 + t]       = red[t] + red[t + 128];
        psum2a[b * 256 + 128 + t] = redq[t] + redq[t + 128];
    }
}

// ==== K4: lin2b (64 blocks x 8 rank-rows, k-tiled) ==========================
__global__ __launch_bounds__(256) void k_lin2b(
        const float* __restrict__ h2a, const float* __restrict__ psum2a,
        const float* __restrict__ g2a, const float* __restrict__ be2a,
        const float* __restrict__ w2b, const float* __restrict__ b2b,
        float* __restrict__ h2b, float* __restrict__ psum2b) {
    __shared__ float wsm[200][33];
    __shared__ float xs[8][36];
    __shared__ float sc[128], sh[128];
    __shared__ float red[256];
    const int b = blockIdx.x, t = threadIdx.x;
    const int nb = b * 8;
    const int nrows = (NK1 - nb) < 0 ? 0 : ((NK1 - nb) < 8 ? (NK1 - nb) : 8);
    if (t < 128) {
        float s = 0.f;
        for (int i = 0; i < 64; ++i) s += psum2a[i * 256 + t];
        red[t] = s;
    }
    {
        float s = 0.f;
        if (t >= 128) for (int i = 0; i < 64; ++i) s += psum2a[i * 256 + t];
        __syncthreads();
        if (t >= 128) red[t] = s;
        __syncthreads();
    }
    if (t < 128) {
        float mu = red[t] * (1.f / NK1);
        float var = red[128 + t] * (1.f / NK1) - mu * mu;
        float sv = g2a[t] * rsqrtf(var + EPS);
        sc[t] = sv; sh[t] = be2a[t] - mu * sv;
    }
    float acc[8];
    float bb = (t < 200) ? b2b[t] : 0.f;
    #pragma unroll
    for (int r = 0; r < 8; ++r) acc[r] = bb;
    for (int kt = 0; kt < 4; ++kt) {
        int k0 = kt * 32;
        __syncthreads();
        for (int i = 0; i < 25; ++i) {
            int e = t + i * 256;
            wsm[e >> 5][e & 31] = w2b[(e >> 5) * 128 + k0 + (e & 31)];
        }
        {
            int r = t >> 5, k = t & 31;
            xs[r][k] = (r < nrows)
                ? bnr(h2a[(nb + r) * 128 + k0 + k], sc[k0 + k], sh[k0 + k]) : 0.f;
        }
        __syncthreads();
        if (t < 200) {
            #pragma unroll
            for (int kq = 0; kq < 8; ++kq) {
                float w0v = wsm[t][4 * kq],     w1v = wsm[t][4 * kq + 1];
                float w2v = wsm[t][4 * kq + 2], w3v = wsm[t][4 * kq + 3];
                #pragma unroll
                for (int r = 0; r < 8; ++r) {
                    float4 xv = *(const float4*)&xs[r][4 * kq];
                    acc[r] = fmaf(xv.x, w0v, fmaf(xv.y, w1v, fmaf(xv.z, w2v, fmaf(xv.w, w3v, acc[r]))));
                }
            }
        }
    }
    if (t < 200) {
        float s = 0.f, q = 0.f;
        #pragma unroll
        for (int r = 0; r < 8; ++r) {
            if (r < nrows) {
                h2b[(nb + r) * 200 + t] = acc[r];
                s += acc[r]; q += acc[r] * acc[r];
            }
        }
        psum2b[b * 400 + t]       = s;
        psum2b[b * 400 + 200 + t] = q;
    }
}

// ==== K5 (16 blocks): BN2b + t2-all + root + on-the-fly remapped scatter2 ===
__global__ __launch_bounds__(256) void k_pool2scat(
        const float* __restrict__ h2b, const float* __restrict__ psum2b,
        const float* __restrict__ g2b, const float* __restrict__ be2b,
        const float* __restrict__ wrel, const float* __restrict__ wroot,
        const float* __restrict__ pb, const int* __restrict__ ei,
        const float* __restrict__ ea, const int* __restrict__ rk_g,
        float* __restrict__ sc2) {
    __shared__ float tt[512], rt[512], acc[512], tmp[400];
    __shared__ float bsc[200], bsh[200];
    const int b = blockIdx.x, t = threadIdx.x;
    for (int idx = t; idx < 400; idx += 256) {
        float s = 0.f;
        for (int i = 0; i < 64; ++i) s += psum2b[i * 400 + idx];
        tmp[idx] = s;
    }
    for (int i = t; i < 512; i += 256) acc[i] = 0.f;
    __syncthreads();
    if (t < 200) {
        float mu = tmp[t] * (1.f / NK1);
        float var = tmp[200 + t] * (1.f / NK1) - mu * mu;
        float sv = g2b[t] * rsqrtf(var + EPS);
        bsc[t] = sv; bsh[t] = be2b[t] - mu * sv;
    }
    __syncthreads();
    // t2-all + root: 4-lane groups, 50 channels each (cached h2b reads)
    {
        const int sub = t & 3, grp = t >> 2;
        float pbv = pb[0];
        for (int p = 0; p < 8; ++p) {
            int n = p * 64 + grp;
            if (n < NK1) {
                const float* hp = h2b + n * 200 + sub * 50;
                float dr = 0.f, dt = 0.f;
                for (int i = 0; i < 50; ++i) {
                    int ch = sub * 50 + i;
                    float v = bnr(hp[i], bsc[ch], bsh[ch]);
                    dr = fmaf(v, wrel[ch], dr);
                    dt = fmaf(v, wroot[ch], dt);
                }
                dr += __shfl_xor(dr, 1, 64); dr += __shfl_xor(dr, 2, 64);
                dt += __shfl_xor(dt, 1, 64); dt += __shfl_xor(dt, 2, 64);
                if (sub == 0) { tt[n] = dr; rt[n] = dt + pbv; }
            }
        }
    }
    __syncthreads();
    // scatter own 2000 original edges, remapped through rk_g on the fly
    for (int e = b * 2000 + t; e < b * 2000 + 2000; e += 256) {
        float w = ea[e];
        if (w != 0.f) {
            int rs = rk_g[ei[e]], rd = rk_g[ei[NE + e]];
            if (rs < NK1 && rd < NK1) atomicAdd(&acc[rd], w * tt[rs]);
        }
    }
    __syncthreads();
    {
        int n = b * 32 + t;
        if (t < 32 && n < NK1) atomicAdd(&sc2[n], rt[n]);
    }
    for (int i = t; i < NK1; i += 256) {
        float v = acc[i];
        if (v != 0.f) atomicAdd(&sc2[i], v);
    }
}

// ==== K6 (1 block x 1024): rank2 + select + maxpool + mlp + log_softmax =====
__global__ __launch_bounds__(1024) void k_final(
        const float* __restrict__ h2b, const float* __restrict__ psum2b,
        const float* __restrict__ g2b, const float* __restrict__ be2b,
        const float* __restrict__ sc2, const float* __restrict__ w3a,
        const float* __restrict__ b3a, const float* __restrict__ w3b,
        const float* __restrict__ b3b, float* __restrict__ out) {
    __shared__ float ss[512], tmp[400];
    __shared__ float bsc[200], bsh[200];
    __shared__ int pn[NK2];
    __shared__ float th[NK2];
    __shared__ float gp[16 * 200];
    __shared__ float g[200], h3[128], o[2];
    const int t = threadIdx.x;
    const int lane = t & 63, wv = t >> 6;

    for (int idx = t; idx < 400; idx += 1024) {
        float s = 0.f;
        for (int i = 0; i < 64; ++i) s += psum2b[i * 400 + idx];
        tmp[idx] = s;
    }
    for (int i = t; i < NK1; i += 1024) ss[i] = sc2[i];
    for (int i = t; i < 16 * 200; i += 1024) gp[i] = -1e30f;
    __syncthreads();
    if (t < 200) {
        float mu = tmp[t] * (1.f / NK1);
        float var = tmp[200 + t] * (1.f / NK1) - mu * mu;
        float sv = g2b[t] * rsqrtf(var + EPS);
        bsc[t] = sv; bsh[t] = be2b[t] - mu * sv;
    }
    __syncthreads();
    if (t < NK1) {
        float s = ss[t];
        int r = 0;
        for (int m = 0; m < NK1; ++m) {
            float x = ss[m];
            r += (x > s) || (x == s && m < t);
        }
        if (r < NK2) { pn[r] = t; th[r] = tanhf(s); }
    }
    __syncthreads();
    for (int j = wv; j < NK2; j += 16) {
        int n = pn[j];
        float tn = th[j];
        #pragma unroll
        for (int jj = 0; jj < 4; ++jj) {
            int ch = lane + 64 * jj;
            if (ch < 200) {
                float v = bnr(h2b[n * 200 + ch], bsc[ch], bsh[ch]) * tn;
                gp[wv * 200 + ch] = fmaxf(gp[wv * 200 + ch], v);
            }
        }
    }
    __syncthreads();
    if (t < 200) {
        float m = gp[t];
        #pragma unroll
        for (int i = 1; i < 16; ++i) m = fmaxf(m, gp[i * 200 + t]);
        g[t] = m;
    }
    __syncthreads();
    for (int r = wv; r < 128; r += 16) {
        float p = 0.f;
        #pragma unroll
        for (int jj = 0; jj < 4; ++jj) {
            int ch = lane + 64 * jj;
            if (ch < 200) p = fmaf(w3a[r * 200 + ch], g[ch], p);
        }
        #pragma unroll
        for (int m = 32; m >= 1; m >>= 1) p += __shfl_xor(p, m, 64);
        if (lane == 0) h3[r] = fmaxf(p + b3a[r], 0.f);
    }
    __syncthreads();
    if (t < 128) {
        int ow = t >> 6;
        float p = w3b[ow * 128 + lane] * h3[lane]
                + w3b[ow * 128 + 64 + lane] * h3[64 + lane];
        #pragma unroll
        for (int m = 32; m >= 1; m >>= 1) p += __shfl_xor(p, m, 64);
        if (lane == 0) o[ow] = fmaxf(p + b3b[ow], 0.f);
    }
    __syncthreads();
    if (t == 0) {
        float m = fmaxf(o[0], o[1]);
        float l = m + logf(expf(o[0] - m) + expf(o[1] - m));
        out[0] = o[0] - l;
        out[1] = o[1] - l;
    }
}

extern "C" void kernel_launch(void* const* d_in, const int* in_sizes, int n_in,
                              void* d_out, int out_size, void* d_ws, size_t ws_size,
                              hipStream_t stream) {
    const float* x    = (const float*)d_in[0];
    const int*   ei   = (const int*)d_in[1];
    const float* ea   = (const float*)d_in[2];
    const float* w0   = (const float*)d_in[3];
    const float* b0   = (const float*)d_in[4];
    const float* g0   = (const float*)d_in[5];
    const float* be0  = (const float*)d_in[6];
    const float* w1   = (const float*)d_in[7];
    const float* b1   = (const float*)d_in[8];
    const float* g1   = (const float*)d_in[9];
    const float* be1  = (const float*)d_in[10];
    const float* w2a  = (const float*)d_in[11];
    const float* b2a  = (const float*)d_in[12];
    const float* g2a  = (const float*)d_in[13];
    const float* be2a = (const float*)d_in[14];
    const float* w2b  = (const float*)d_in[15];
    const float* b2b  = (const float*)d_in[16];
    const float* g2b  = (const float*)d_in[17];
    const float* be2b = (const float*)d_in[18];
    const float* w3a  = (const float*)d_in[19];
    const float* b3a  = (const float*)d_in[20];
    const float* w3b  = (const float*)d_in[21];
    const float* b3b  = (const float*)d_in[22];
    const float* p1_wrel  = (const float*)d_in[23];
    const float* p1_wroot = (const float*)d_in[24];
    const float* p1_b     = (const float*)d_in[25];
    const float* p2_wrel  = (const float*)d_in[26];
    const float* p2_wroot = (const float*)d_in[27];
    const float* p2_b     = (const float*)d_in[28];

    float* ws = (float*)d_ws;
    float* h1     = ws;                  // 64000
    float* h2a    = ws + 64000;          // 64000
    float* h2b    = ws + 128000;         // 100000
    float* psum1  = ws + 228000;         // 8192  (64 x 128)
    float* psum2a = ws + 236192;         // 16384 (64 x 256)
    float* psum2b = ws + 252576;         // 25600 (64 x 400)
    float* sc1    = ws + 278176;         // 1000
    float* sc2    = ws + 279176;         // 500
    int*   rk_g   = (int*)(ws + 279676); // 1000
    float* out    = (float*)d_out;

    k_lin01<<<64, 256, 0, stream>>>(x, w0, b0, g0, be0, w1, b1, h1, psum1, sc1, sc2);
    k_pool1scat<<<16, 256, 0, stream>>>(h1, psum1, g1, be1, p1_wrel, p1_wroot, p1_b,
                                        ei, ea, sc1);
    k_rank1_lin2a<<<64, 256, 0, stream>>>(h1, psum1, g1, be1, sc1, w2a, b2a,
                                          h2a, psum2a, rk_g);
    k_lin2b<<<64, 256, 0, stream>>>(h2a, psum2a, g2a, be2a, w2b, b2b, h2b, psum2b);
    k_pool2scat<<<16, 256, 0, stream>>>(h2b, psum2b, g2b, be2b, p2_wrel, p2_wroot, p2_b,
                                        ei, ea, rk_g, sc2);
    k_final<<<1, 1024, 0, stream>>>(h2b, psum2b, g2b, be2b, sc2, w3a, b3a, w3b, b3b, out);
}

// Round 14
// 111.087 us; speedup vs baseline: 1.2278x; 1.2278x over previous
//
#include <hip/hip_runtime.h>
#include <math.h>

#define EPS 1e-5f
#define N0 1000
#define NK1 500
#define NK2 100
#define NE 32000

__device__ __forceinline__ float bnr(float h, float sc, float sh) {
    float v = fmaf(h, sc, sh);
    return v > 0.f ? v : 0.f;
}

// ==== K1: lin0+lin1 fused (64 blocks x 16 nodes) + zero sc1/sc2 =============
// BN0 stats computed in closed form from the 9 moments of x (h0 linear in x).
__global__ __launch_bounds__(256) void k_lin01(
        const float* __restrict__ x, const float* __restrict__ w0,
        const float* __restrict__ b0, const float* __restrict__ g0,
        const float* __restrict__ be0, const float* __restrict__ w1,
        const float* __restrict__ b1, float* __restrict__ h1,
        float* __restrict__ psum1, float* __restrict__ sc1, float* __restrict__ sc2) {
    __shared__ float xs[16][68], wsm[64][65];
    __shared__ float sc0[64], sh0[64];
    __shared__ float redA[256], redB[256];
    __shared__ float mom[4][9];
    const int b = blockIdx.x, t = threadIdx.x;
    const int c = t & 63, slot = t >> 6;
    const int lane = t & 63, wv = t >> 6;
    const int nb = b * 16;

    int gid = b * 256 + t;
    if (gid < 1000) sc1[gid] = 0.f;
    else if (gid < 1500) sc2[gid - 1000] = 0.f;

    // --- 9 moments of x: coalesced pass + shuffle reduce ---
    {
        float mm[9] = {0.f, 0.f, 0.f, 0.f, 0.f, 0.f, 0.f, 0.f, 0.f};
        for (int n = t; n < N0; n += 256) {
            float x0 = x[3 * n], x1 = x[3 * n + 1], x2 = x[3 * n + 2];
            mm[0] += x0; mm[1] += x1; mm[2] += x2;
            mm[3] += x0 * x0; mm[4] += x1 * x1; mm[5] += x2 * x2;
            mm[6] += x0 * x1; mm[7] += x0 * x2; mm[8] += x1 * x2;
        }
        #pragma unroll
        for (int k = 0; k < 9; ++k) {
            #pragma unroll
            for (int msk = 32; msk >= 1; msk >>= 1) mm[k] += __shfl_xor(mm[k], msk, 64);
        }
        if (lane < 9) mom[wv][lane] = mm[lane] * 0.f;  // placeholder overwritten below
        if (lane == 0) {
            #pragma unroll
            for (int k = 0; k < 9; ++k) mom[wv][k] = mm[k];
        }
        __syncthreads();
        if (t < 64) {
            float M0 = mom[0][0] + mom[1][0] + mom[2][0] + mom[3][0];
            float M1 = mom[0][1] + mom[1][1] + mom[2][1] + mom[3][1];
            float M2 = mom[0][2] + mom[1][2] + mom[2][2] + mom[3][2];
            float P00 = mom[0][3] + mom[1][3] + mom[2][3] + mom[3][3];
            float P11 = mom[0][4] + mom[1][4] + mom[2][4] + mom[3][4];
            float P22 = mom[0][5] + mom[1][5] + mom[2][5] + mom[3][5];
            float P01 = mom[0][6] + mom[1][6] + mom[2][6] + mom[3][6];
            float P02 = mom[0][7] + mom[1][7] + mom[2][7] + mom[3][7];
            float P12 = mom[0][8] + mom[1][8] + mom[2][8] + mom[3][8];
            float wa = w0[t * 3], wb = w0[t * 3 + 1], wc = w0[t * 3 + 2], bb = b0[t];
            float lin = wa * M0 + wb * M1 + wc * M2;
            float S = lin + (float)N0 * bb;
            float Q = wa * wa * P00 + wb * wb * P11 + wc * wc * P22
                    + 2.f * (wa * wb * P01 + wa * wc * P02 + wb * wc * P12)
                    + 2.f * bb * lin + (float)N0 * bb * bb;
            float mu = S * (1.f / N0);
            float var = Q * (1.f / N0) - mu * mu;
            float sv = g0[t] * rsqrtf(var + EPS);
            sc0[t] = sv; sh0[t] = be0[t] - mu * sv;
        }
        __syncthreads();
    }
    // y0 tile (recompute h0 + BN0 relu) + w1 staging
    for (int i = 0; i < 4; ++i) {
        int e = t + i * 256;
        int r = e >> 6, cc = e & 63;
        int n = nb + r;
        float v = 0.f;
        if (n < N0) {
            float h = fmaf(w0[cc * 3], x[n * 3],
                      fmaf(w0[cc * 3 + 1], x[n * 3 + 1],
                      fmaf(w0[cc * 3 + 2], x[n * 3 + 2], b0[cc])));
            v = bnr(h, sc0[cc], sh0[cc]);
        }
        xs[r][cc] = v;
    }
    for (int i = 0; i < 16; ++i) {
        int e = t + i * 256;
        wsm[e >> 6][e & 63] = w1[e];
    }
    __syncthreads();
    const int r0 = slot * 4;
    float bb1 = b1[c];
    float a0 = bb1, a1 = bb1, a2 = bb1, a3 = bb1;
    #pragma unroll
    for (int kq = 0; kq < 16; ++kq) {
        float w0v = wsm[c][4 * kq],     w1v = wsm[c][4 * kq + 1];
        float w2v = wsm[c][4 * kq + 2], w3v = wsm[c][4 * kq + 3];
        float4 x0 = *(const float4*)&xs[r0 + 0][4 * kq];
        float4 x1 = *(const float4*)&xs[r0 + 1][4 * kq];
        float4 x2 = *(const float4*)&xs[r0 + 2][4 * kq];
        float4 x3 = *(const float4*)&xs[r0 + 3][4 * kq];
        a0 = fmaf(x0.x, w0v, fmaf(x0.y, w1v, fmaf(x0.z, w2v, fmaf(x0.w, w3v, a0))));
        a1 = fmaf(x1.x, w0v, fmaf(x1.y, w1v, fmaf(x1.z, w2v, fmaf(x1.w, w3v, a1))));
        a2 = fmaf(x2.x, w0v, fmaf(x2.y, w1v, fmaf(x2.z, w2v, fmaf(x2.w, w3v, a2))));
        a3 = fmaf(x3.x, w0v, fmaf(x3.y, w1v, fmaf(x3.z, w2v, fmaf(x3.w, w3v, a3))));
    }
    float av[4] = {a0, a1, a2, a3};
    float sacc = 0.f, qacc = 0.f;
    #pragma unroll
    for (int i = 0; i < 4; ++i) {
        int n = nb + r0 + i;
        if (n < N0) {
            h1[n * 64 + c] = av[i];
            sacc += av[i]; qacc += av[i] * av[i];
        }
    }
    __syncthreads();
    redA[t] = sacc; redB[t] = qacc;
    __syncthreads();
    if (t < 64) {
        // transposed psum layout: [channel][64 blocks]
        psum1[t * 64 + b]        = redA[t] + redA[t + 64] + redA[t + 128] + redA[t + 192];
        psum1[(64 + t) * 64 + b] = redB[t] + redB[t + 64] + redB[t + 128] + redB[t + 192];
    }
}

__device__ __forceinline__ float sum64c(const float* p) {
    const float4* p4 = (const float4*)p;
    float4 a = p4[0];
    #pragma unroll
    for (int i = 1; i < 16; ++i) {
        float4 v = p4[i];
        a.x += v.x; a.y += v.y; a.z += v.z; a.w += v.w;
    }
    return (a.x + a.y) + (a.z + a.w);
}
__device__ __forceinline__ float sum32c(const float* p) {
    const float4* p4 = (const float4*)p;
    float4 a = p4[0];
    #pragma unroll
    for (int i = 1; i < 8; ++i) {
        float4 v = p4[i];
        a.x += v.x; a.y += v.y; a.z += v.z; a.w += v.w;
    }
    return (a.x + a.y) + (a.z + a.w);
}

// ==== K2 (16 blocks): BN1 + t1-all + root-all + scatter1 ====================
__global__ __launch_bounds__(256) void k_pool1scat(
        const float* __restrict__ h1, const float* __restrict__ psum1,
        const float* __restrict__ g1, const float* __restrict__ be1,
        const float* __restrict__ wrel, const float* __restrict__ wroot,
        const float* __restrict__ pb, const int* __restrict__ ei,
        const float* __restrict__ ea, float* __restrict__ sc1) {
    __shared__ float tt[1008], rt[1008], acc[1008];
    __shared__ float bsc[64], bsh[64];
    __shared__ float red[128];
    const int b = blockIdx.x, t = threadIdx.x;
    if (t < 128) red[t] = sum64c(psum1 + t * 64);
    for (int i = t; i < 1008; i += 256) acc[i] = 0.f;
    __syncthreads();
    if (t < 64) {
        float mu = red[t] * (1.f / N0);
        float var = red[64 + t] * (1.f / N0) - mu * mu;
        float sv = g1[t] * rsqrtf(var + EPS);
        bsc[t] = sv; bsh[t] = be1[t] - mu * sv;
    }
    __syncthreads();
    // t1-all + root-all: 4-lane groups, 16 channels each (cached h1 reads)
    {
        const int sub = t & 3, grp = t >> 2;
        float wrv[16], wov[16], scv[16], shv[16];
        #pragma unroll
        for (int i = 0; i < 16; ++i) {
            int ch = sub * 16 + i;
            wrv[i] = wrel[ch]; wov[i] = wroot[ch];
            scv[i] = bsc[ch];  shv[i] = bsh[ch];
        }
        float pbv = pb[0];
        for (int p = 0; p < 16; ++p) {
            int n = p * 64 + grp;
            if (n < N0) {
                const float* hp = h1 + n * 64 + sub * 16;
                float dr = 0.f, dt = 0.f;
                #pragma unroll
                for (int i = 0; i < 16; ++i) {
                    float v = bnr(hp[i], scv[i], shv[i]);
                    dr = fmaf(v, wrv[i], dr);
                    dt = fmaf(v, wov[i], dt);
                }
                dr += __shfl_xor(dr, 1, 64); dr += __shfl_xor(dr, 2, 64);
                dt += __shfl_xor(dt, 1, 64); dt += __shfl_xor(dt, 2, 64);
                if (sub == 0) { tt[n] = dr; rt[n] = dt + pbv; }
            }
        }
    }
    __syncthreads();
    for (int e = b * 2000 + t; e < b * 2000 + 2000; e += 256) {
        float w = ea[e];
        if (w != 0.f) atomicAdd(&acc[ei[NE + e]], w * tt[ei[e]]);
    }
    __syncthreads();
    {
        int n = b * 63 + t;
        if (t < 63 && n < N0) atomicAdd(&sc1[n], rt[n]);
    }
    for (int i = t; i < N0; i += 256) {
        float v = acc[i];
        if (v != 0.f) atomicAdd(&sc1[i], v);
    }
}

// ==== K3: rank1 + select + lin2a owner-computes (64 blocks x 16 nodes) ======
__global__ __launch_bounds__(256) void k_rank1_lin2a(
        const float* __restrict__ h1, const float* __restrict__ psum1,
        const float* __restrict__ g1, const float* __restrict__ be1,
        const float* __restrict__ sc1, const float* __restrict__ w2a,
        const float* __restrict__ b2a, float* __restrict__ h2a,
        float* __restrict__ psum2a, int* __restrict__ rk_g) {
    __shared__ float ss[N0];
    __shared__ float xp[16][68];
    __shared__ float wsm[128][65];
    __shared__ float bsc[64], bsh[64];
    __shared__ float red[256], redq[256];
    __shared__ int rloc[16], svj[16];
    __shared__ float thv[16];
    __shared__ int nsS;
    const int b = blockIdx.x, t = threadIdx.x;
    const int lane = t & 63, wv = t >> 6;
    const int nb = b * 16;
    const int nn = (N0 - nb) < 0 ? 0 : ((N0 - nb) < 16 ? (N0 - nb) : 16);

    for (int i = t; i < N0; i += 256) ss[i] = sc1[i];
    if (t < 128) red[t] = sum64c(psum1 + t * 64);
    __syncthreads();
    if (t < 64) {
        float mu = red[t] * (1.f / N0);
        float var = red[64 + t] * (1.f / N0) - mu * mu;
        float sv = g1[t] * rsqrtf(var + EPS);
        bsc[t] = sv; bsh[t] = be1[t] - mu * sv;
    }
    __syncthreads();
    for (int it = 0; it < 4; ++it) {
        int j = it * 4 + wv;
        int n = nb + j;
        if (j < nn) {
            float s = ss[n];
            int r = 0;
            for (int m = lane; m < N0; m += 64) {
                float x = ss[m];
                r += (x > s) || (x == s && m < n);
            }
            #pragma unroll
            for (int msk = 32; msk >= 1; msk >>= 1) r += __shfl_xor(r, msk, 64);
            if (lane == 0) { rk_g[n] = r; rloc[j] = r; }
        } else if (lane == 0) rloc[j] = 1 << 20;
    }
    __syncthreads();
    if (t == 0) {
        int c_ = 0;
        for (int j = 0; j < 16; ++j)
            if (rloc[j] < NK1) { svj[c_] = j; ++c_; }
        nsS = c_;
    }
    __syncthreads();
    const int ns = nsS;
    if (t < ns) thv[t] = tanhf(ss[nb + svj[t]]);
    __syncthreads();
    for (int e = t; e < 16 * 64; e += 256) {
        int i = e >> 6, c = e & 63;
        xp[i][c] = (i < ns) ? bnr(h1[(nb + svj[i]) * 64 + c], bsc[c], bsh[c]) * thv[i] : 0.f;
    }
    for (int e = t; e < 128 * 64; e += 256)
        wsm[e >> 6][e & 63] = w2a[e];
    __syncthreads();
    const int c2 = t & 127, half = t >> 7;
    float hac[8];
    {
        float bb = b2a[c2];
        #pragma unroll
        for (int i = 0; i < 8; ++i) hac[i] = bb;
    }
    #pragma unroll
    for (int kq = 0; kq < 16; ++kq) {
        float w0v = wsm[c2][4 * kq],     w1v = wsm[c2][4 * kq + 1];
        float w2v = wsm[c2][4 * kq + 2], w3v = wsm[c2][4 * kq + 3];
        #pragma unroll
        for (int i = 0; i < 8; ++i) {
            float4 x4 = *(const float4*)&xp[half * 8 + i][4 * kq];
            hac[i] = fmaf(x4.x, w0v, fmaf(x4.y, w1v, fmaf(x4.z, w2v, fmaf(x4.w, w3v, hac[i]))));
        }
    }
    float s = 0.f, q = 0.f;
    #pragma unroll
    for (int i = 0; i < 8; ++i) {
        int sl = half * 8 + i;
        if (sl < ns) {
            int r = rloc[svj[sl]];
            h2a[r * 128 + c2] = hac[i];
            s += hac[i]; q += hac[i] * hac[i];
        }
    }
    __syncthreads();
    red[t] = s; redq[t] = q;
    __syncthreads();
    if (t < 128) {
        // transposed psum layout: [channel][64 blocks]
        psum2a[t * 64 + b]         = red[t] + red[t + 128];
        psum2a[(128 + t) * 64 + b] = redq[t] + redq[t + 128];
    }
}

// ==== K4 (32 blocks x 16 rank-rows): BN2a + lin2b, w2b direct-from-global ===
__global__ __launch_bounds__(256) void k_lin2b(
        const float* __restrict__ h2a, const float* __restrict__ psum2a,
        const float* __restrict__ g2a, const float* __restrict__ be2a,
        const float* __restrict__ w2b, const float* __restrict__ b2b,
        float* __restrict__ h2b, float* __restrict__ psum2b) {
    __shared__ float zL[16][132];
    __shared__ float sc[128], sh[128];
    __shared__ float red[256];
    const int b = blockIdx.x, t = threadIdx.x;
    const int nb = b * 16;
    const int nrows = (NK1 - nb) < 16 ? (NK1 - nb) : 16;
    if (t < 256) red[t] = sum64c(psum2a + t * 64);
    __syncthreads();
    if (t < 128) {
        float mu = red[t] * (1.f / NK1);
        float var = red[128 + t] * (1.f / NK1) - mu * mu;
        float sv = g2a[t] * rsqrtf(var + EPS);
        sc[t] = sv; sh[t] = be2a[t] - mu * sv;
    }
    __syncthreads();
    for (int e = t; e < 16 * 128; e += 256) {
        int r = e >> 7, k = e & 127;
        zL[r][k] = (r < nrows) ? bnr(h2a[(nb + r) * 128 + k], sc[k], sh[k]) : 0.f;
    }
    __syncthreads();
    if (t < 200) {
        float acc[16];
        float bb = b2b[t];
        #pragma unroll
        for (int i = 0; i < 16; ++i) acc[i] = bb;
        for (int kq = 0; kq < 32; ++kq) {
            float4 w4 = *(const float4*)&w2b[t * 128 + 4 * kq];
            #pragma unroll
            for (int i = 0; i < 16; ++i) {
                float4 z4 = *(const float4*)&zL[i][4 * kq];
                acc[i] = fmaf(z4.x, w4.x, fmaf(z4.y, w4.y, fmaf(z4.z, w4.z, fmaf(z4.w, w4.w, acc[i]))));
            }
        }
        float s = 0.f, q = 0.f;
        #pragma unroll
        for (int i = 0; i < 16; ++i) {
            if (i < nrows) {
                h2b[(nb + i) * 200 + t] = acc[i];
                s += acc[i]; q += acc[i] * acc[i];
            }
        }
        // transposed psum layout: [channel][32 blocks]
        psum2b[t * 32 + b]         = s;
        psum2b[(200 + t) * 32 + b] = q;
    }
}

// ==== K5 (16 blocks): BN2b + t2-all + root + on-the-fly remapped scatter2 ===
__global__ __launch_bounds__(256) void k_pool2scat(
        const float* __restrict__ h2b, const float* __restrict__ psum2b,
        const float* __restrict__ g2b, const float* __restrict__ be2b,
        const float* __restrict__ wrel, const float* __restrict__ wroot,
        const float* __restrict__ pb, const int* __restrict__ ei,
        const float* __restrict__ ea, const int* __restrict__ rk_g,
        float* __restrict__ sc2) {
    __shared__ float tt[512], rt[512], acc[512], tmp[400];
    __shared__ float bsc[200], bsh[200];
    const int b = blockIdx.x, t = threadIdx.x;
    for (int idx = t; idx < 400; idx += 256) tmp[idx] = sum32c(psum2b + idx * 32);
    for (int i = t; i < 512; i += 256) acc[i] = 0.f;
    __syncthreads();
    if (t < 200) {
        float mu = tmp[t] * (1.f / NK1);
        float var = tmp[200 + t] * (1.f / NK1) - mu * mu;
        float sv = g2b[t] * rsqrtf(var + EPS);
        bsc[t] = sv; bsh[t] = be2b[t] - mu * sv;
    }
    __syncthreads();
    {
        const int sub = t & 3, grp = t >> 2;
        float pbv = pb[0];
        for (int p = 0; p < 8; ++p) {
            int n = p * 64 + grp;
            if (n < NK1) {
                const float* hp = h2b + n * 200 + sub * 50;
                float dr = 0.f, dt = 0.f;
                for (int i = 0; i < 50; ++i) {
                    int ch = sub * 50 + i;
                    float v = bnr(hp[i], bsc[ch], bsh[ch]);
                    dr = fmaf(v, wrel[ch], dr);
                    dt = fmaf(v, wroot[ch], dt);
                }
                dr += __shfl_xor(dr, 1, 64); dr += __shfl_xor(dr, 2, 64);
                dt += __shfl_xor(dt, 1, 64); dt += __shfl_xor(dt, 2, 64);
                if (sub == 0) { tt[n] = dr; rt[n] = dt + pbv; }
            }
        }
    }
    __syncthreads();
    for (int e = b * 2000 + t; e < b * 2000 + 2000; e += 256) {
        float w = ea[e];
        if (w != 0.f) {
            int rs = rk_g[ei[e]], rd = rk_g[ei[NE + e]];
            if (rs < NK1 && rd < NK1) atomicAdd(&acc[rd], w * tt[rs]);
        }
    }
    __syncthreads();
    {
        int n = b * 32 + t;
        if (t < 32 && n < NK1) atomicAdd(&sc2[n], rt[n]);
    }
    for (int i = t; i < NK1; i += 256) {
        float v = acc[i];
        if (v != 0.f) atomicAdd(&sc2[i], v);
    }
}

// ==== K6 (1 block x 1024): rank2 + select + maxpool + mlp + log_softmax =====
__global__ __launch_bounds__(1024) void k_final(
        const float* __restrict__ h2b, const float* __restrict__ psum2b,
        const float* __restrict__ g2b, const float* __restrict__ be2b,
        const float* __restrict__ sc2, const float* __restrict__ w3a,
        const float* __restrict__ b3a, const float* __restrict__ w3b,
        const float* __restrict__ b3b, float* __restrict__ out) {
    __shared__ float ss[512], tmp[400];
    __shared__ float bsc[200], bsh[200];
    __shared__ int pn[NK2];
    __shared__ float th[NK2];
    __shared__ float gp[16 * 200];
    __shared__ float g[200], h3[128], o[2];
    const int t = threadIdx.x;
    const int lane = t & 63, wv = t >> 6;

    for (int idx = t; idx < 400; idx += 1024) tmp[idx] = sum32c(psum2b + idx * 32);
    for (int i = t; i < NK1; i += 1024) ss[i] = sc2[i];
    for (int i = t; i < 16 * 200; i += 1024) gp[i] = -1e30f;
    __syncthreads();
    if (t < 200) {
        float mu = tmp[t] * (1.f / NK1);
        float var = tmp[200 + t] * (1.f / NK1) - mu * mu;
        float sv = g2b[t] * rsqrtf(var + EPS);
        bsc[t] = sv; bsh[t] = be2b[t] - mu * sv;
    }
    __syncthreads();
    // rank2: wave-per-node, lane-strided scan
    for (int n = wv; n < NK1; n += 16) {
        float s = ss[n];
        int r = 0;
        for (int m = lane; m < NK1; m += 64) {
            float x = ss[m];
            r += (x > s) || (x == s && m < n);
        }
        #pragma unroll
        for (int msk = 32; msk >= 1; msk >>= 1) r += __shfl_xor(r, msk, 64);
        if (lane == 0 && r < NK2) { pn[r] = n; th[r] = tanhf(s); }
    }
    __syncthreads();
    for (int j = wv; j < NK2; j += 16) {
        int n = pn[j];
        float tn = th[j];
        #pragma unroll
        for (int jj = 0; jj < 4; ++jj) {
            int ch = lane + 64 * jj;
            if (ch < 200) {
                float v = bnr(h2b[n * 200 + ch], bsc[ch], bsh[ch]) * tn;
                gp[wv * 200 + ch] = fmaxf(gp[wv * 200 + ch], v);
            }
        }
    }
    __syncthreads();
    if (t < 200) {
        float m = gp[t];
        #pragma unroll
        for (int i = 1; i < 16; ++i) m = fmaxf(m, gp[i * 200 + t]);
        g[t] = m;
    }
    __syncthreads();
    for (int r = wv; r < 128; r += 16) {
        float p = 0.f;
        #pragma unroll
        for (int jj = 0; jj < 4; ++jj) {
            int ch = lane + 64 * jj;
            if (ch < 200) p = fmaf(w3a[r * 200 + ch], g[ch], p);
        }
        #pragma unroll
        for (int m = 32; m >= 1; m >>= 1) p += __shfl_xor(p, m, 64);
        if (lane == 0) h3[r] = fmaxf(p + b3a[r], 0.f);
    }
    __syncthreads();
    if (t < 128) {
        int ow = t >> 6;
        float p = w3b[ow * 128 + lane] * h3[lane]
                + w3b[ow * 128 + 64 + lane] * h3[64 + lane];
        #pragma unroll
        for (int m = 32; m >= 1; m >>= 1) p += __shfl_xor(p, m, 64);
        if (lane == 0) o[ow] = fmaxf(p + b3b[ow], 0.f);
    }
    __syncthreads();
    if (t == 0) {
        float m = fmaxf(o[0], o[1]);
        float l = m + logf(expf(o[0] - m) + expf(o[1] - m));
        out[0] = o[0] - l;
        out[1] = o[1] - l;
    }
}

extern "C" void kernel_launch(void* const* d_in, const int* in_sizes, int n_in,
                              void* d_out, int out_size, void* d_ws, size_t ws_size,
                              hipStream_t stream) {
    const float* x    = (const float*)d_in[0];
    const int*   ei   = (const int*)d_in[1];
    const float* ea   = (const float*)d_in[2];
    const float* w0   = (const float*)d_in[3];
    const float* b0   = (const float*)d_in[4];
    const float* g0   = (const float*)d_in[5];
    const float* be0  = (const float*)d_in[6];
    const float* w1   = (const float*)d_in[7];
    const float* b1   = (const float*)d_in[8];
    const float* g1   = (const float*)d_in[9];
    const float* be1  = (const float*)d_in[10];
    const float* w2a  = (const float*)d_in[11];
    const float* b2a  = (const float*)d_in[12];
    const float* g2a  = (const float*)d_in[13];
    const float* be2a = (const float*)d_in[14];
    const float* w2b  = (const float*)d_in[15];
    const float* b2b  = (const float*)d_in[16];
    const float* g2b  = (const float*)d_in[17];
    const float* be2b = (const float*)d_in[18];
    const float* w3a  = (const float*)d_in[19];
    const float* b3a  = (const float*)d_in[20];
    const float* w3b  = (const float*)d_in[21];
    const float* b3b  = (const float*)d_in[22];
    const float* p1_wrel  = (const float*)d_in[23];
    const float* p1_wroot = (const float*)d_in[24];
    const float* p1_b     = (const float*)d_in[25];
    const float* p2_wrel  = (const float*)d_in[26];
    const float* p2_wroot = (const float*)d_in[27];
    const float* p2_b     = (const float*)d_in[28];

    float* ws = (float*)d_ws;
    float* h1     = ws;                  // 64000
    float* h2a    = ws + 64000;          // 64000
    float* h2b    = ws + 128000;         // 100000
    float* psum1  = ws + 228000;         // 8192  ([128][64])
    float* psum2a = ws + 236192;         // 16384 ([256][64])
    float* psum2b = ws + 252576;         // 12800 ([400][32])
    float* sc1    = ws + 265376;         // 1000
    float* sc2    = ws + 266376;         // 500
    int*   rk_g   = (int*)(ws + 266876); // 1000
    float* out    = (float*)d_out;

    k_lin01<<<64, 256, 0, stream>>>(x, w0, b0, g0, be0, w1, b1, h1, psum1, sc1, sc2);
    k_pool1scat<<<16, 256, 0, stream>>>(h1, psum1, g1, be1, p1_wrel, p1_wroot, p1_b,
                                        ei, ea, sc1);
    k_rank1_lin2a<<<64, 256, 0, stream>>>(h1, psum1, g1, be1, sc1, w2a, b2a,
                                          h2a, psum2a, rk_g);
    k_lin2b<<<32, 256, 0, stream>>>(h2a, psum2a, g2a, be2a, w2b, b2b, h2b, psum2b);
    k_pool2scat<<<16, 256, 0, stream>>>(h2b, psum2b, g2b, be2b, p2_wrel, p2_wroot, p2_b,
                                        ei, ea, rk_g, sc2);
    k_final<<<1, 1024, 0, stream>>>(h2b, psum2b, g2b, be2b, sc2, w3a, b3a, w3b, b3b, out);
}